// Round 5
// baseline (1111.316 us; speedup 1.0000x reference)
//
#include <hip/hip_runtime.h>

#define HH 20
#define WW 20
#define TT 96
#define BB 64
#define SIG 306
#define NFC 17
#define FROW 16        // feat channels stored (12 conv + 4 raw); tch analytic
#define PIXSTRIDE 516  // 32t*16ch + 4 pad floats per pixel in feat LDS
#define CHUNK 32
#define NCHUNK 3
#define XT 199         // xs per-t stride (>=192; %32=7 spreads win-read banks)
#define KTOT 122400
#define KSLAB 120
#define NSLAB 4        // 480 K per mlp1 block
#define NKBLK 255      // 255 * 480 = 122400

// ---------------------------------------------------------------------------
// Kernel 1: conv + signature -> sig workspace.
// Block = 256 thr (4 waves) = one (b, 4x4-pixel tile). Grid 64*25 = 1600.
// CHUNK=32: each conv lane computes 2 (pixel,t) rows per chunk so every
// LDS weight-broadcast read (the dominant LDS-pipe load) is reused 2x.
// ---------------------------------------------------------------------------
__global__ __launch_bounds__(256, 2) void sig_kernel(
    const float* __restrict__ x,   // (64,96,4,20,20)
    const float* __restrict__ cw,  // (12,4,3,3)
    const float* __restrict__ cb,  // (12,)
    float* __restrict__ sig)       // (64,122400)
{
  __shared__ __align__(16) float feat[16 * PIXSTRIDE];   // 33.0 KB
  __shared__ __align__(16) float xs[CHUNK * XT];         // 25.5 KB
  __shared__ __align__(16) float wlds[12 * 48];          // [k][ci][dy][4]
  __shared__ float wb[12];

  const int tid = threadIdx.x;
  const int blk = blockIdx.x;
  const int b = blk / 25;
  const int tile = blk % 25;
  const int th4 = (tile / 5) * 4, tw4 = (tile % 5) * 4;
  const float* xb0 = x + (size_t)b * TT * 1600;

  // ---- stage conv weights (once) ----
  #pragma unroll
  for (int r = 0; r < 3; r++) {
    int idx = r * 256 + tid;
    if (idx < 576) {
      int k = idx / 48, rem = idx % 48;
      int ci = rem / 12, r2 = rem % 12, dy = r2 >> 2, dx = r2 & 3;
      wlds[idx] = (dx < 3) ? cw[k * 36 + ci * 9 + dy * 3 + dx] : 0.f;
    }
  }
  if (tid < 12) wb[tid] = cb[tid];

  // ---- staging precompute: 2304 = 9*256 halo values per 16-t half ----
  int g_off[9], l_off[9];
  bool valid[9];
  #pragma unroll
  for (int r = 0; r < 9; r++) {
    int idx = r * 256 + tid;                 // < 2304
    int t = idx / 144, q = idx % 144;
    int ci = q / 36, pos = q % 36, row = pos / 6, col = pos % 6;
    int gr = th4 - 1 + row, gc = tw4 - 1 + col;
    valid[r] = (gr >= 0 && gr < HH && gc >= 0 && gc < WW);
    g_off[r] = t * 1600 + ci * 400 + (valid[r] ? gr * WW + gc : 0);
    l_off[r] = t * XT + ci * 48 + row * 8 + col;
  }

  // ---- conv mapping: lane = pix*16 + tt, handles tt and tt+16 ----
  const int cpix = tid >> 4, ctt = tid & 15;
  const int cpy = cpix >> 2, cpx = cpix & 3;

  // ---- phase-2 mapping: lane = pix*16 + (it*4 + jt) ----
  const int p2 = tid >> 4;
  const int rr = tid & 15, it = rr >> 2, jt = rr & 3;
  const int i0 = it * 4, j0 = jt * 4;

  float accv[4][4];
  float f0a[4], f0b[4], pa[4], pb[4], fsum[4];
  #pragma unroll
  for (int i = 0; i < 4; i++) {
    f0a[i] = 0.f; f0b[i] = 0.f; pa[i] = 0.f; pb[i] = 0.f; fsum[i] = 0.f;
    #pragma unroll
    for (int j = 0; j < 4; j++) accv[i][j] = 0.f;
  }

  __syncthreads();   // weights staged
  float breg[12];
  #pragma unroll
  for (int k = 0; k < 12; k++) breg[k] = wb[k];

  for (int chunk = 0; chunk < NCHUNK; chunk++) {
    // ===== stage x halo: 32 t = two 16-t halves, 18 loads in flight =====
    {
      const float* xbc = xb0 + (size_t)chunk * CHUNK * 1600;
      float rg[18];
      #pragma unroll
      for (int r = 0; r < 9; r++) rg[r] = valid[r] ? xbc[g_off[r]] : 0.f;
      #pragma unroll
      for (int r = 0; r < 9; r++) rg[9 + r] = valid[r] ? xbc[g_off[r] + 16 * 1600] : 0.f;
      #pragma unroll
      for (int r = 0; r < 9; r++) xs[l_off[r]] = rg[r];
      #pragma unroll
      for (int r = 0; r < 9; r++) xs[l_off[r] + 16 * XT] = rg[9 + r];
    }
    __syncthreads();   // xs ready (prev phase-2 done before feat rewrite)

    // ===== conv: 2 rows (ctt, ctt+16), weight reads shared =====
    {
      float winA[4][9], winB[4][9];
      const int wbA = ctt * XT, wbB = (ctt + 16) * XT;
      #pragma unroll
      for (int ci = 0; ci < 4; ci++)
        #pragma unroll
        for (int dy = 0; dy < 3; dy++)
          #pragma unroll
          for (int dxx = 0; dxx < 3; dxx++) {
            const int o = ci * 48 + (cpy + dy) * 8 + (cpx + dxx);
            winA[ci][dy * 3 + dxx] = xs[wbA + o];
            winB[ci][dy * 3 + dxx] = xs[wbB + o];
          }

      float fkA[12], fkB[12];
      #pragma unroll
      for (int k = 0; k < 12; k++) {
        float aA = breg[k], aB = breg[k];
        #pragma unroll
        for (int ci = 0; ci < 4; ci++) {
          #pragma unroll
          for (int dy = 0; dy < 3; dy++) {
            const float4 w4 = *reinterpret_cast<const float4*>(
                &wlds[k * 48 + ci * 12 + dy * 4]);
            aA += winA[ci][dy * 3 + 0] * w4.x + winA[ci][dy * 3 + 1] * w4.y +
                  winA[ci][dy * 3 + 2] * w4.z;
            aB += winB[ci][dy * 3 + 0] * w4.x + winB[ci][dy * 3 + 1] * w4.y +
                  winB[ci][dy * 3 + 2] * w4.z;
          }
        }
        fkA[k] = aA; fkB[k] = aB;
      }
      float* frA = &feat[cpix * PIXSTRIDE + ctt * FROW];
      float* frB = frA + 16 * FROW;
      *reinterpret_cast<float4*>(frA + 0)  = make_float4(fkA[0], fkA[1], fkA[2], fkA[3]);
      *reinterpret_cast<float4*>(frA + 4)  = make_float4(fkA[4], fkA[5], fkA[6], fkA[7]);
      *reinterpret_cast<float4*>(frA + 8)  = make_float4(fkA[8], fkA[9], fkA[10], fkA[11]);
      *reinterpret_cast<float4*>(frA + 12) = make_float4(winA[0][4], winA[1][4], winA[2][4], winA[3][4]);
      *reinterpret_cast<float4*>(frB + 0)  = make_float4(fkB[0], fkB[1], fkB[2], fkB[3]);
      *reinterpret_cast<float4*>(frB + 4)  = make_float4(fkB[4], fkB[5], fkB[6], fkB[7]);
      *reinterpret_cast<float4*>(frB + 8)  = make_float4(fkB[8], fkB[9], fkB[10], fkB[11]);
      *reinterpret_cast<float4*>(frB + 12) = make_float4(winB[0][4], winB[1][4], winB[2][4], winB[3][4]);
    }
    __syncthreads();   // feat ready

    // ===== phase 2: 4x4 tile of the 16x16 lvl2 core =====
    int tstart = 0;
    if (chunk == 0) {
      const float* r0 = &feat[p2 * PIXSTRIDE];
      const float4 a4 = *reinterpret_cast<const float4*>(r0 + i0);
      const float4 b4 = *reinterpret_cast<const float4*>(r0 + j0);
      f0a[0] = a4.x; f0a[1] = a4.y; f0a[2] = a4.z; f0a[3] = a4.w;
      f0b[0] = b4.x; f0b[1] = b4.y; f0b[2] = b4.z; f0b[3] = b4.w;
      #pragma unroll
      for (int i = 0; i < 4; i++) { pa[i] = f0a[i]; pb[i] = f0b[i]; fsum[i] = f0a[i]; }
      tstart = 1;
    }

    for (int tt = tstart; tt < CHUNK; tt++) {
      const float* row = &feat[p2 * PIXSTRIDE + tt * FROW];
      const float4 a4 = *reinterpret_cast<const float4*>(row + i0);
      const float4 b4 = *reinterpret_cast<const float4*>(row + j0);
      float fa[4] = {a4.x, a4.y, a4.z, a4.w};
      float fb[4] = {b4.x, b4.y, b4.z, b4.w};
      float av[4], bv[4];
      #pragma unroll
      for (int i = 0; i < 4; i++) {
        av[i] = 0.5f * (fa[i] + pa[i]) - f0a[i];
        bv[i] = fb[i] - pb[i];
        fsum[i] += fa[i];
        pa[i] = fa[i]; pb[i] = fb[i];
      }
      #pragma unroll
      for (int i = 0; i < 4; i++)
        #pragma unroll
        for (int j = 0; j < 4; j++) accv[i][j] += av[i] * bv[j];
    }
    __syncthreads();
  }

  // ===== write sig: core tile + analytic tch row/col/corner + lvl1 =====
  {
    const int ph = th4 + (p2 >> 2), pw = tw4 + (p2 & 3);
    float* sb = sig + (size_t)b * KTOT + (size_t)(ph * WW + pw) * SIG;
    #pragma unroll
    for (int ii = 0; ii < 4; ii++)
      #pragma unroll
      for (int jj = 0; jj < 4; jj++)
        sb[NFC + (i0 + ii) * NFC + (j0 + jj)] = accv[ii][jj];
    if (jt == 0) {
      #pragma unroll
      for (int ii = 0; ii < 4; ii++) {
        const int c = i0 + ii;
        const float f0 = f0a[ii], f95 = pa[ii], fs = fsum[ii];
        sb[c] = f95 - f0;                                            // lvl1
        sb[NFC + c * NFC + 16] = (fs - 95.5f * f0 - 0.5f * f95) * (1.f / 95.f);
        sb[NFC + 16 * NFC + c] = (95.5f * f95 + 0.5f * f0 - fs) * (1.f / 95.f);
      }
      if (it == 0) { sb[16] = 1.0f; sb[NFC + 16 * NFC + 16] = 0.5f; }
    }
  }
}

// ---------------------------------------------------------------------------
// Kernel 2: MLP-1 K-split GEMM. 255 blocks x 480-K slabs.
// ATOMIC=false: partials -> part[(blk,64,32)] (no atomics; w1 staged in LDS).
// ATOMIC=true : fallback, atomicAdd into part (= zeroed acc of 64x32).
// ---------------------------------------------------------------------------
template<bool ATOMIC>
__global__ __launch_bounds__(256) void mlp1_gemm(
    const float* __restrict__ sig, const float* __restrict__ w1,
    float* __restrict__ part)
{
  __shared__ __align__(16) float ldsT[KSLAB * 68];   // [k][b] 32.6 KB
  __shared__ __align__(16) float wls[KSLAB * 32];    // [k][n] 15.4 KB
  const int tid = threadIdx.x;
  const int n = tid & 31, bq = tid >> 5;
  const int k0 = blockIdx.x * (KSLAB * NSLAB);

  float a8[8];
  #pragma unroll
  for (int i = 0; i < 8; i++) a8[i] = 0.f;

  for (int s = 0; s < NSLAB; s++) {
    const int ks = k0 + s * KSLAB;
    __syncthreads();   // protect LDS reuse across slabs
    #pragma unroll
    for (int r = 0; r < 30; r++) {             // 64*120/256
      int idx = r * 256 + tid;
      int b = idx / KSLAB, kk = idx % KSLAB;
      ldsT[kk * 68 + b] = sig[(size_t)b * KTOT + ks + kk];
    }
    #pragma unroll
    for (int r = 0; r < 15; r++) {             // 120*32/256
      int idx = r * 256 + tid;
      wls[idx] = w1[(size_t)ks * 32 + idx];
    }
    __syncthreads();

    #pragma unroll 4
    for (int kk = 0; kk < KSLAB; kk++) {
      const float w = wls[kk * 32 + n];
      const float4 s0 = *reinterpret_cast<const float4*>(&ldsT[kk * 68 + bq * 8]);
      const float4 s1 = *reinterpret_cast<const float4*>(&ldsT[kk * 68 + bq * 8 + 4]);
      a8[0] += s0.x * w; a8[1] += s0.y * w; a8[2] += s0.z * w; a8[3] += s0.w * w;
      a8[4] += s1.x * w; a8[5] += s1.y * w; a8[6] += s1.z * w; a8[7] += s1.w * w;
    }
  }

  if (ATOMIC) {
    #pragma unroll
    for (int i = 0; i < 8; i++)
      atomicAdd(&part[(bq * 8 + i) * 32 + n], a8[i]);
  } else {
    const size_t pb = (size_t)blockIdx.x * (BB * 32);
    #pragma unroll
    for (int i = 0; i < 8; i++)
      part[pb + (bq * 8 + i) * 32 + n] = a8[i];
  }
}

// ---------------------------------------------------------------------------
// Kernel 3: partial-reduce + MLP layers 2-4. 8 blocks x 256 thr;
// thread (b,n) sums npart partials then 32-lane shuffle-broadcast dots.
// ---------------------------------------------------------------------------
__global__ __launch_bounds__(256) void mlp_tail(
    const float* __restrict__ part, int npart, const float* __restrict__ b1,
    const float* __restrict__ w2, const float* __restrict__ b2,
    const float* __restrict__ w3, const float* __restrict__ b3,
    const float* __restrict__ w4, const float* __restrict__ b4,
    float* __restrict__ out)
{
  const int tid = threadIdx.x;
  const int n = tid & 31;
  const int b = blockIdx.x * 8 + (tid >> 5);
  const int lane = tid & 63;
  const int grp = lane & 32;

  float s = 0.f;
  #pragma unroll 4
  for (int p = 0; p < npart; p++)
    s += part[(size_t)p * (BB * 32) + b * 32 + n];

  float h = fmaxf(s + b1[n], 0.f);

  float v = b2[n];
  #pragma unroll
  for (int k = 0; k < 32; k++)
    v += __shfl(h, grp + k, 64) * w2[k * 32 + n];
  h = fmaxf(v, 0.f);

  v = b3[n];
  #pragma unroll
  for (int k = 0; k < 32; k++)
    v += __shfl(h, grp + k, 64) * w3[k * 32 + n];
  h = fmaxf(v, 0.f);

  float p = h * w4[n];
  #pragma unroll
  for (int o = 16; o >= 1; o >>= 1) p += __shfl_xor(p, o, 64);
  if (n == 0) out[b] = p + b4[0];
}

extern "C" void kernel_launch(void* const* d_in, const int* in_sizes, int n_in,
                              void* d_out, int out_size, void* d_ws, size_t ws_size,
                              hipStream_t stream) {
  const float* x  = (const float*)d_in[0];
  const float* cw = (const float*)d_in[1];
  const float* cb = (const float*)d_in[2];
  const float* w1 = (const float*)d_in[3];
  const float* b1 = (const float*)d_in[4];
  const float* w2 = (const float*)d_in[5];
  const float* b2 = (const float*)d_in[6];
  const float* w3 = (const float*)d_in[7];
  const float* b3 = (const float*)d_in[8];
  const float* w4 = (const float*)d_in[9];
  const float* b4 = (const float*)d_in[10];
  float* out = (float*)d_out;

  const size_t sig_bytes  = (size_t)BB * KTOT * sizeof(float);        // 31.3 MB
  const size_t part_bytes = (size_t)NKBLK * BB * 32 * sizeof(float);  // 2.09 MB
  float* sigm = (float*)d_ws;
  float* part = (float*)((char*)d_ws + sig_bytes);

  sig_kernel<<<dim3(1600), dim3(256), 0, stream>>>(x, cw, cb, sigm);

  if (ws_size >= sig_bytes + part_bytes) {
    mlp1_gemm<false><<<dim3(NKBLK), dim3(256), 0, stream>>>(sigm, w1, part);
    mlp_tail<<<dim3(8), dim3(256), 0, stream>>>(part, NKBLK, b1, w2, b2, w3, b3, w4, b4, out);
  } else {
    // fallback: atomic accumulation into a small acc after sig
    float* acc = part;   // 8 KB
    hipMemsetAsync(acc, 0, BB * 32 * sizeof(float), stream);
    mlp1_gemm<true><<<dim3(NKBLK), dim3(256), 0, stream>>>(sigm, w1, acc);
    mlp_tail<<<dim3(8), dim3(256), 0, stream>>>(acc, 1, b1, w2, b2, w3, b3, w4, b4, out);
  }
}

// Round 6
// 275.755 us; speedup vs baseline: 4.0301x; 4.0301x over previous
//
#include <hip/hip_runtime.h>

#define HH 20
#define WW 20
#define TT 96
#define BB 64
#define SIG 306
#define NFC 17
#define FROW 16        // feat channels stored (12 conv + 4 raw); tch analytic
#define PIXSTRIDE 260  // 16t*16ch + 4 pad floats per pixel in feat LDS
#define CHUNK 16
#define NCHUNK 6
#define XT 199         // xs per-t stride (>=192; odd -> bank spread)
#define KTOT 122400
#define KSLAB 120
#define NSLAB 4        // 480 K per mlp1 block
#define NKBLK 255      // 255 * 480 = 122400

// ---------------------------------------------------------------------------
// Kernel 0: reorder conv weights to [ci][dy][k*3+dx] (36-float slabs) so the
// sig kernel can fetch each (ci,dy) slab with contiguous scalar loads.
// ---------------------------------------------------------------------------
__global__ __launch_bounds__(64) void prep_weights(
    const float* __restrict__ cw, float* __restrict__ cwr)
{
  const int i = threadIdx.x;
  #pragma unroll
  for (int r = 0; r < 7; r++) {
    int idx = r * 64 + i;
    if (idx < 432) {
      int ci = idx / 108, r2 = idx % 108, dy = r2 / 36, r3 = r2 % 36;
      int k = r3 / 3, dx = r3 % 3;
      cwr[idx] = cw[k * 36 + ci * 9 + dy * 3 + dx];
    }
  }
}

// ---------------------------------------------------------------------------
// Kernel 1: conv + signature -> sig workspace.
// Block = 256 thr (4 waves) = one (b, 4x4-pixel tile). Grid 64*25 = 1600.
// Conv weights come in via the SCALAR path (uniform-address loads -> s_load,
// SGPR operand in v_fma): zero LDS-pipe cost. Bias omitted: the signature is
// exactly bias-invariant (all sig terms have zero coefficient sum over t).
// ---------------------------------------------------------------------------
__global__ __launch_bounds__(256) void sig_kernel(
    const float* __restrict__ x,    // (64,96,4,20,20)
    const float* __restrict__ cwr,  // (432,) reordered weights
    float* __restrict__ sig)        // (64,122400)
{
  __shared__ __align__(16) float feat[16 * PIXSTRIDE];   // 16.6 KB
  __shared__ __align__(16) float xs[CHUNK * XT];         // 12.7 KB

  const int tid = threadIdx.x;
  const int blk = blockIdx.x;
  const int b = blk / 25;
  const int tile = blk % 25;
  const int th4 = (tile / 5) * 4, tw4 = (tile % 5) * 4;
  const float* xb0 = x + (size_t)b * TT * 1600;

  // ---- staging precompute: 2304 = 9*256 halo values per chunk ----
  int g_off[9], l_off[9];   // g_off = -1 for OOB (SAME padding -> 0)
  #pragma unroll
  for (int r = 0; r < 9; r++) {
    int idx = r * 256 + tid;                 // < 2304
    int t = idx / 144, q = idx % 144;
    int ci = q / 36, pos = q % 36, row = pos / 6, col = pos % 6;
    int gr = th4 - 1 + row, gc = tw4 - 1 + col;
    bool valid = (gr >= 0 && gr < HH && gc >= 0 && gc < WW);
    g_off[r] = valid ? (t * 1600 + ci * 400 + gr * WW + gc) : -1;
    l_off[r] = t * XT + ci * 48 + row * 8 + col;
  }

  // ---- conv mapping: lane = pix*16 + tt ----
  const int cpix = tid >> 4, ctt = tid & 15;
  const int cpy = cpix >> 2, cpx = cpix & 3;

  // ---- phase-2 mapping: lane = pix*16 + (it*4 + jt) ----
  const int p2 = tid >> 4;
  const int rr = tid & 15, it = rr >> 2, jt = rr & 3;
  const int i0 = it * 4, j0 = jt * 4;

  float accv[4][4];
  float f0a[4], f0b[4], pa[4], pb[4], fsum[4];
  #pragma unroll
  for (int i = 0; i < 4; i++) {
    f0a[i] = 0.f; f0b[i] = 0.f; pa[i] = 0.f; pb[i] = 0.f; fsum[i] = 0.f;
    #pragma unroll
    for (int j = 0; j < 4; j++) accv[i][j] = 0.f;
  }

  for (int chunk = 0; chunk < NCHUNK; chunk++) {
    // ===== stage x halo for this chunk (9 coalesced loads/thread) =====
    {
      const float* xbc = xb0 + (size_t)chunk * CHUNK * 1600;
      float rg[9];
      #pragma unroll
      for (int r = 0; r < 9; r++)
        rg[r] = (g_off[r] >= 0) ? xbc[g_off[r]] : 0.f;
      #pragma unroll
      for (int r = 0; r < 9; r++) xs[l_off[r]] = rg[r];
    }
    __syncthreads();   // xs ready (prev phase-2 done before feat rewrite)

    // ===== conv: this lane's (pixel, t) 16-channel feat row =====
    {
      float win[4][9];
      const int wb2 = ctt * XT;
      #pragma unroll
      for (int ci = 0; ci < 4; ci++)
        #pragma unroll
        for (int dy = 0; dy < 3; dy++)
          #pragma unroll
          for (int dxx = 0; dxx < 3; dxx++)
            win[ci][dy * 3 + dxx] = xs[wb2 + ci * 48 + (cpy + dy) * 8 + (cpx + dxx)];

      float fk[12];
      #pragma unroll
      for (int k = 0; k < 12; k++) fk[k] = 0.f;
      #pragma unroll
      for (int ci = 0; ci < 4; ci++) {
        #pragma unroll
        for (int dy = 0; dy < 3; dy++) {
          const float* wp = cwr + (ci * 3 + dy) * 36;   // uniform -> s_load
          const float w0a = win[ci][dy * 3 + 0];
          const float w1a = win[ci][dy * 3 + 1];
          const float w2a = win[ci][dy * 3 + 2];
          #pragma unroll
          for (int k = 0; k < 12; k++)
            fk[k] += w0a * wp[k * 3 + 0] + w1a * wp[k * 3 + 1] + w2a * wp[k * 3 + 2];
        }
      }
      float* fr = &feat[cpix * PIXSTRIDE + ctt * FROW];
      *reinterpret_cast<float4*>(fr + 0)  = make_float4(fk[0], fk[1], fk[2], fk[3]);
      *reinterpret_cast<float4*>(fr + 4)  = make_float4(fk[4], fk[5], fk[6], fk[7]);
      *reinterpret_cast<float4*>(fr + 8)  = make_float4(fk[8], fk[9], fk[10], fk[11]);
      *reinterpret_cast<float4*>(fr + 12) = make_float4(win[0][4], win[1][4], win[2][4], win[3][4]);
    }
    __syncthreads();   // feat ready

    // ===== phase 2: 4x4 tile of the 16x16 lvl2 core =====
    int tstart = 0;
    if (chunk == 0) {
      const float* r0 = &feat[p2 * PIXSTRIDE];
      const float4 a4 = *reinterpret_cast<const float4*>(r0 + i0);
      const float4 b4 = *reinterpret_cast<const float4*>(r0 + j0);
      f0a[0] = a4.x; f0a[1] = a4.y; f0a[2] = a4.z; f0a[3] = a4.w;
      f0b[0] = b4.x; f0b[1] = b4.y; f0b[2] = b4.z; f0b[3] = b4.w;
      #pragma unroll
      for (int i = 0; i < 4; i++) { pa[i] = f0a[i]; pb[i] = f0b[i]; fsum[i] = f0a[i]; }
      tstart = 1;
    }

    for (int tt = tstart; tt < CHUNK; tt++) {
      const float* row = &feat[p2 * PIXSTRIDE + tt * FROW];
      const float4 a4 = *reinterpret_cast<const float4*>(row + i0);
      const float4 b4 = *reinterpret_cast<const float4*>(row + j0);
      float fa[4] = {a4.x, a4.y, a4.z, a4.w};
      float fb[4] = {b4.x, b4.y, b4.z, b4.w};
      float av[4], bv[4];
      #pragma unroll
      for (int i = 0; i < 4; i++) {
        av[i] = 0.5f * (fa[i] + pa[i]) - f0a[i];
        bv[i] = fb[i] - pb[i];
        fsum[i] += fa[i];
        pa[i] = fa[i]; pb[i] = fb[i];
      }
      #pragma unroll
      for (int i = 0; i < 4; i++)
        #pragma unroll
        for (int j = 0; j < 4; j++) accv[i][j] += av[i] * bv[j];
    }
    __syncthreads();
  }

  // ===== write sig: core tile + analytic tch row/col/corner + lvl1 =====
  {
    const int ph = th4 + (p2 >> 2), pw = tw4 + (p2 & 3);
    float* sb = sig + (size_t)b * KTOT + (size_t)(ph * WW + pw) * SIG;
    #pragma unroll
    for (int ii = 0; ii < 4; ii++)
      #pragma unroll
      for (int jj = 0; jj < 4; jj++)
        sb[NFC + (i0 + ii) * NFC + (j0 + jj)] = accv[ii][jj];
    if (jt == 0) {
      #pragma unroll
      for (int ii = 0; ii < 4; ii++) {
        const int c = i0 + ii;
        const float f0 = f0a[ii], f95 = pa[ii], fs = fsum[ii];
        sb[c] = f95 - f0;                                            // lvl1
        sb[NFC + c * NFC + 16] = (fs - 95.5f * f0 - 0.5f * f95) * (1.f / 95.f);
        sb[NFC + 16 * NFC + c] = (95.5f * f95 + 0.5f * f0 - fs) * (1.f / 95.f);
      }
      if (it == 0) { sb[16] = 1.0f; sb[NFC + 16 * NFC + 16] = 0.5f; }
    }
  }
}

// ---------------------------------------------------------------------------
// Kernel 2: MLP-1 K-split GEMM. 255 blocks x 480-K slabs.
// ATOMIC=false: partials -> part[(blk,64,32)] (no atomics; w1 staged in LDS).
// ATOMIC=true : fallback, atomicAdd into part (= zeroed acc of 64x32).
// ---------------------------------------------------------------------------
template<bool ATOMIC>
__global__ __launch_bounds__(256) void mlp1_gemm(
    const float* __restrict__ sig, const float* __restrict__ w1,
    float* __restrict__ part)
{
  __shared__ __align__(16) float ldsT[KSLAB * 68];   // [k][b] 32.6 KB
  __shared__ __align__(16) float wls[KSLAB * 32];    // [k][n] 15.4 KB
  const int tid = threadIdx.x;
  const int n = tid & 31, bq = tid >> 5;
  const int k0 = blockIdx.x * (KSLAB * NSLAB);

  float a8[8];
  #pragma unroll
  for (int i = 0; i < 8; i++) a8[i] = 0.f;

  for (int s = 0; s < NSLAB; s++) {
    const int ks = k0 + s * KSLAB;
    __syncthreads();   // protect LDS reuse across slabs
    #pragma unroll
    for (int r = 0; r < 30; r++) {             // 64*120/256
      int idx = r * 256 + tid;
      int b = idx / KSLAB, kk = idx % KSLAB;
      ldsT[kk * 68 + b] = sig[(size_t)b * KTOT + ks + kk];
    }
    #pragma unroll
    for (int r = 0; r < 15; r++) {             // 120*32/256
      int idx = r * 256 + tid;
      wls[idx] = w1[(size_t)ks * 32 + idx];
    }
    __syncthreads();

    #pragma unroll 4
    for (int kk = 0; kk < KSLAB; kk++) {
      const float w = wls[kk * 32 + n];
      const float4 s0 = *reinterpret_cast<const float4*>(&ldsT[kk * 68 + bq * 8]);
      const float4 s1 = *reinterpret_cast<const float4*>(&ldsT[kk * 68 + bq * 8 + 4]);
      a8[0] += s0.x * w; a8[1] += s0.y * w; a8[2] += s0.z * w; a8[3] += s0.w * w;
      a8[4] += s1.x * w; a8[5] += s1.y * w; a8[6] += s1.z * w; a8[7] += s1.w * w;
    }
  }

  if (ATOMIC) {
    #pragma unroll
    for (int i = 0; i < 8; i++)
      atomicAdd(&part[(bq * 8 + i) * 32 + n], a8[i]);
  } else {
    const size_t pb = (size_t)blockIdx.x * (BB * 32);
    #pragma unroll
    for (int i = 0; i < 8; i++)
      part[pb + (bq * 8 + i) * 32 + n] = a8[i];
  }
}

// ---------------------------------------------------------------------------
// Kernel 3: partial-reduce + MLP layers 2-4. 8 blocks x 256 thr;
// thread (b,n) sums npart partials then 32-lane shuffle-broadcast dots.
// ---------------------------------------------------------------------------
__global__ __launch_bounds__(256) void mlp_tail(
    const float* __restrict__ part, int npart, const float* __restrict__ b1,
    const float* __restrict__ w2, const float* __restrict__ b2,
    const float* __restrict__ w3, const float* __restrict__ b3,
    const float* __restrict__ w4, const float* __restrict__ b4,
    float* __restrict__ out)
{
  const int tid = threadIdx.x;
  const int n = tid & 31;
  const int b = blockIdx.x * 8 + (tid >> 5);
  const int lane = tid & 63;
  const int grp = lane & 32;

  float s = 0.f;
  #pragma unroll 4
  for (int p = 0; p < npart; p++)
    s += part[(size_t)p * (BB * 32) + b * 32 + n];

  float h = fmaxf(s + b1[n], 0.f);

  float v = b2[n];
  #pragma unroll
  for (int k = 0; k < 32; k++)
    v += __shfl(h, grp + k, 64) * w2[k * 32 + n];
  h = fmaxf(v, 0.f);

  v = b3[n];
  #pragma unroll
  for (int k = 0; k < 32; k++)
    v += __shfl(h, grp + k, 64) * w3[k * 32 + n];
  h = fmaxf(v, 0.f);

  float p = h * w4[n];
  #pragma unroll
  for (int o = 16; o >= 1; o >>= 1) p += __shfl_xor(p, o, 64);
  if (n == 0) out[b] = p + b4[0];
}

extern "C" void kernel_launch(void* const* d_in, const int* in_sizes, int n_in,
                              void* d_out, int out_size, void* d_ws, size_t ws_size,
                              hipStream_t stream) {
  const float* x  = (const float*)d_in[0];
  const float* cw = (const float*)d_in[1];
  const float* b1 = (const float*)d_in[4];
  const float* w1 = (const float*)d_in[3];
  const float* w2 = (const float*)d_in[5];
  const float* b2 = (const float*)d_in[6];
  const float* w3 = (const float*)d_in[7];
  const float* b3 = (const float*)d_in[8];
  const float* w4 = (const float*)d_in[9];
  const float* b4 = (const float*)d_in[10];
  float* out = (float*)d_out;

  const size_t sig_bytes  = (size_t)BB * KTOT * sizeof(float);        // 31.3 MB
  const size_t part_bytes = (size_t)NKBLK * BB * 32 * sizeof(float);  // 2.09 MB
  float* sigm = (float*)d_ws;

  if (ws_size >= sig_bytes + part_bytes + 2048) {
    float* part = (float*)((char*)d_ws + sig_bytes);
    float* cwr  = (float*)((char*)d_ws + sig_bytes + part_bytes);
    prep_weights<<<dim3(1), dim3(64), 0, stream>>>(cw, cwr);
    sig_kernel<<<dim3(1600), dim3(256), 0, stream>>>(x, cwr, sigm);
    mlp1_gemm<false><<<dim3(NKBLK), dim3(256), 0, stream>>>(sigm, w1, part);
    mlp_tail<<<dim3(8), dim3(256), 0, stream>>>(part, NKBLK, b1, w2, b2, w3, b3, w4, b4, out);
  } else {
    // fallback: atomic accumulation into a small acc after sig
    float* acc = (float*)((char*)d_ws + sig_bytes);        // 8 KB
    float* cwr = (float*)((char*)d_ws + sig_bytes + 8192);
    prep_weights<<<dim3(1), dim3(64), 0, stream>>>(cw, cwr);
    hipMemsetAsync(acc, 0, BB * 32 * sizeof(float), stream);
    sig_kernel<<<dim3(1600), dim3(256), 0, stream>>>(x, cwr, sigm);
    mlp1_gemm<true><<<dim3(NKBLK), dim3(256), 0, stream>>>(sigm, w1, acc);
    mlp_tail<<<dim3(8), dim3(256), 0, stream>>>(acc, 1, b1, w2, b2, w3, b3, w4, b4, out);
  }
}